// Round 19
// baseline (1542.035 us; speedup 1.0000x reference)
//
#include <hip/hip_runtime.h>
#include <hip/hip_bf16.h>
#include <stdint.h>

// Problem dims (fixed by reference)
#define Bq    8192
#define Hh    8
#define Dd    16
#define Kk    16
#define Nn    4096
#define DFf   16
#define ROWS  (Bq*Hh)          // 65536
#define COLS  (Dd*Kk)          // 256
#define EPSF  1e-6f

typedef unsigned long long u64;
typedef unsigned int u32;
typedef __attribute__((ext_vector_type(4)))  int i32x4;
typedef __attribute__((ext_vector_type(16))) int i32x16;

// async global->LDS, 16B per lane; LDS dest = wave-uniform base + lane*16
#define GLOAD_LDS(g, l) __builtin_amdgcn_global_load_lds( \
    (const __attribute__((address_space(1))) u32*)(g), \
    (__attribute__((address_space(3))) u32*)(l), 16, 0, 0)

// ---------- helpers ----------
__device__ __forceinline__ float dot4(float4 a, float4 b) {
    return fmaf(a.x, b.x, fmaf(a.y, b.y, fmaf(a.z, b.z, a.w * b.w)));
}
__device__ __forceinline__ float wave_sum(float v) {
    #pragma unroll
    for (int m = 32; m > 0; m >>= 1) v += __shfl_xor(v, m, 64);
    return v;
}
__device__ __forceinline__ float wave_max(float v) {
    #pragma unroll
    for (int m = 32; m > 0; m >>= 1) v = fmaxf(v, __shfl_xor(v, m, 64));
    return v;
}
__device__ __forceinline__ u32 f32_sortable(float f) {
    u32 u = __float_as_uint(f);
    return (u & 0x80000000u) ? ~u : (u | 0x80000000u);
}
__device__ __forceinline__ int q8(float v, float s) {
    int q = (int)__builtin_rintf(v * s);          // RNE
    return q > 127 ? 127 : (q < -127 ? -127 : q);
}
// exact fp32 rerank, R2's accepted expression tree (sequential fmaf over 64 float4s)
__device__ __forceinline__ void exact_rerank(const float* __restrict__ X,
                                             const float* __restrict__ CB,
                                             const float* __restrict__ xx,
                                             const float* __restrict__ cbn,
                                             int row, int col,
                                             u64* __restrict__ best) {
    const float4* xp = (const float4*)(X + (size_t)row * COLS);
    const float4* cp = (const float4*)(CB + (size_t)col * COLS);
    float d = 0.f;
    #pragma unroll 8
    for (int q = 0; q < 64; ++q) {
        float4 a = xp[q], b = cp[q];
        d = fmaf(a.x, b.x, d); d = fmaf(a.y, b.y, d);
        d = fmaf(a.z, b.z, d); d = fmaf(a.w, b.w, d);
    }
    float d2e = fmaf(-2.f, d, xx[row]) + cbn[col];
    u64 pk = ((u64)f32_sortable(d2e) << 32) | (u32)col;
    atomicMin(&best[row], pk);
}

// ---------- kernel -1: init atomics (ws is 0xAA-poisoned) ----------
__global__ void k_init(u32* cbn_max, u32* maxx, u32* maxc) {
    if (threadIdx.x == 0) { *cbn_max = 0u; *maxx = 0u; *maxc = 0u; }
}

// ---------- kernel 0: xx[r], max|x|, init best ----------
__global__ __launch_bounds__(256) void k_prep(const float* __restrict__ X,
                                              float* __restrict__ xx,
                                              u64* __restrict__ best,
                                              u32* __restrict__ maxx) {
    int r    = blockIdx.x * 4 + (threadIdx.x >> 6);
    int lane = threadIdx.x & 63;
    float4 v = *reinterpret_cast<const float4*>(X + (size_t)r * COLS + lane * 4);
    float s = wave_sum(v.x*v.x + v.y*v.y + v.z*v.z + v.w*v.w);
    float am = wave_max(fmaxf(fmaxf(fabsf(v.x), fabsf(v.y)),
                              fmaxf(fabsf(v.z), fabsf(v.w))));
    if (lane == 0) {
        xx[r] = s; best[r] = ~0ull;
        atomicMax(maxx, __float_as_uint(am));   // nonneg float bits monotone
    }
}

// ---------- kernel 1: codebook fp32 + cbn + acc-order cbn_f + max|c| ----------
__global__ __launch_bounds__(256) void k_codebook(const float* __restrict__ fc,
                                                  const float* __restrict__ Wi,
                                                  const float* __restrict__ Wo,
                                                  float* __restrict__ CB,
                                                  float* __restrict__ cbn,
                                                  float* __restrict__ cbn_f,
                                                  u32* __restrict__ cbn_max,
                                                  u32* __restrict__ maxc) {
    int n = blockIdx.x, tid = threadIdx.x;
    int o = tid >> 4, k = tid & 15;
    __shared__ float fcs[256], wis[256], wos[256], hs[256], sq[256], am[256];
    fcs[tid] = fc[(size_t)n * 256 + tid];
    wis[tid] = Wi[tid];
    wos[tid] = Wo[tid];
    __syncthreads();
    float hp = 0.f;
    #pragma unroll
    for (int i = 0; i < 16; ++i) hp = fmaf(wis[o*16 + i], fcs[i*16 + k], hp);
    hs[tid] = hp;
    __syncthreads();
    float h0 = hs[o * 16];
    float x3 = h0 * h0 * h0;
    float inner = 0.7978845608028654f * fmaf(0.044715f, x3, h0);
    float g = 0.5f * h0 * (1.f + tanhf(inner));
    float hg = hp * g;
    __syncthreads();
    hs[tid] = hg;
    __syncthreads();
    float cv = 0.f;
    #pragma unroll
    for (int i = 0; i < 16; ++i) cv = fmaf(wos[o*16 + i], hs[i*16 + k], cv);
    CB[(size_t)n * 256 + tid] = cv;
    sq[tid] = cv * cv;
    am[tid] = fabsf(cv);
    __syncthreads();
    #pragma unroll
    for (int st = 128; st > 0; st >>= 1) {
        if (tid < st) { sq[tid] += sq[tid + st]; am[tid] = fmaxf(am[tid], am[tid + st]); }
        __syncthreads();
    }
    if (tid == 0) {
        cbn[n] = sq[0];
        atomicMax(cbn_max, __float_as_uint(sq[0]));
        atomicMax(maxc, __float_as_uint(am[0]));
        int tile = n >> 5, c = n & 31;
        int h = (c >> 2) & 1, r = (c & 3) | ((c >> 3) << 2);
        cbn_f[tile * 32 + h * 16 + r] = sq[0];
    }
}

// ---------- kernel 2a: quantize X -> i8 (row-major) ----------
__global__ __launch_bounds__(256) void k_quantx(const float* __restrict__ X,
                                                signed char* __restrict__ Xq,
                                                const u32* __restrict__ maxx) {
    int r    = blockIdx.x * 4 + (threadIdx.x >> 6);
    int lane = threadIdx.x & 63;
    float sx = 127.f / __uint_as_float(*maxx);
    float4 v = *reinterpret_cast<const float4*>(X + (size_t)r * COLS + lane * 4);
    u32 p = (u32)(u32(q8(v.x, sx)) & 0xff)
          | ((u32)(q8(v.y, sx) & 0xff) << 8)
          | ((u32)(q8(v.z, sx) & 0xff) << 16)
          | ((u32)(q8(v.w, sx) & 0xff) << 24);
    *reinterpret_cast<u32*>(Xq + (size_t)r * COLS + lane * 4) = p;
}

// ---------- kernel 2b: quantize CB -> i8 in 32x32x32 FRAGMENT order ----------
// CBq layout: per 32-code tile (8 KB), frag ks (0..7) is 1 KB:
// lane l = h*32 + c holds 16 i8 of code (tile*32+c), k = ks*32 + h*16 .. +15.
__global__ __launch_bounds__(256) void k_quantcb(const float* __restrict__ CB,
                                                 signed char* __restrict__ CBq,
                                                 const u32* __restrict__ maxc) {
    int n = blockIdx.x, tid = threadIdx.x;
    __shared__ signed char qs[256];
    float sc = 127.f / __uint_as_float(*maxc);
    qs[tid] = (signed char)q8(CB[(size_t)n * 256 + tid], sc);
    __syncthreads();
    if (tid < 16) {
        int ks = tid >> 1, h = tid & 1;
        int tile = n >> 5, c = n & 31;
        size_t off = (size_t)tile * 8192 + ks * 1024 + (h * 32 + c) * 16;
        *reinterpret_cast<uint4*>(CBq + off) =
            *reinterpret_cast<const uint4*>(&qs[tid * 16]);
    }
}

// ---------- kernel 3: swapped-operand i8 32x32x32 screen ----------
// R16's HW-verified structure (512 blocks x 256 threads, 4 waves x 32 x-rows,
// lane owns one x-row, single-barrier 2-phase, pair of tiles per step,
// 6-slot stale-eviction candidates) with bf16 -> INT8:
//   - mfma_i32_32x32x32_i8: K=32/instr -> 8 MFMA/tile (was 16); i32 acc EXACT
//   - codebook bytes halve: LDS reads 16 b128/pair (was 32), staging 16 KB
//   - af[8] = 32 VGPR (was 64)
// Screen margin is now a DERIVED bound (quant err only, RNE +-0.5 ulp):
//   dot_err sd = sqrt((xx*dc^2 + cbn*dx^2)/3), dx=maxx/254, dc=maxc/254
//   dlt = 2*8sd + 2*256*dx*dc + 0.01  (8-sigma + deterministic cross term)
// acc < 2^22 -> cvt_f32_i32 exact. Candidate safety as before: rmin only
// decreases, argmin + exact ties never evicted; exact fp32 rerank merges.
__global__ __launch_bounds__(256, 2) void k_screen_fused(
        const signed char* __restrict__ Xq,
        const signed char* __restrict__ CBq,
        const float* __restrict__ X,
        const float* __restrict__ CB,
        const float* __restrict__ cbn,
        const float* __restrict__ cbn_f,
        const float* __restrict__ xx,
        u64* __restrict__ best,
        const u32* __restrict__ cbn_max,
        const u32* __restrict__ maxx,
        const u32* __restrict__ maxc) {
    __shared__ __align__(16) signed char Bs[2][16384];  // 2 x (pair of 8KB tiles)
    __shared__ float cbn_fs[Nn];                        // 16 KB, acc-order

    const int tid  = threadIdx.x;
    const int lane = tid & 63;
    const int w    = tid >> 6;           // wave 0..3
    const int cl   = lane & 31;          // this lane's x-row (D col)
    const int kh   = lane >> 5;          // k-half / code-half
    const int bmBase = blockIdx.x * 128; // 32 x-rows per wave
    const int myrow  = bmBase + w * 32 + cl;

// stage tile PAIR P (tiles 2P, 2P+1) into Bs[buf]: 4 gloads/thread
#define STAGE2(P_, buf) do { \
        int _P = (P_); \
        _Pragma("unroll") \
        for (int _i = 0; _i < 4; ++_i) { \
            int _half = _i >> 1; \
            int _f = (_i & 1) * 4 + w; \
            const signed char* _g = CBq + (size_t)(_P * 2 + _half) * 8192 \
                                  + _f * 1024 + lane * 16; \
            GLOAD_LDS(_g, &Bs[(buf)][_half * 8192 + _f * 1024]); \
        } \
    } while (0)

    // cbn_f -> LDS (acc-order, all 4096 codes)
    #pragma unroll
    for (int j = 0; j < 4; ++j)
        *reinterpret_cast<float4*>(&cbn_fs[tid * 16 + j * 4]) =
            *reinterpret_cast<const float4*>(&cbn_f[tid * 16 + j * 4]);

    // X fragments (B-operand): af[ks], lane holds x-row myrow,
    // k = ks*32 + kh*16 .. +15 (16 i8 = 4 regs)
    i32x4 af[8];
    {
        const signed char* ap = Xq + ((size_t)myrow << 8) + kh * 16;
        #pragma unroll
        for (int ks = 0; ks < 8; ++ks)
            af[ks] = *reinterpret_cast<const i32x4*>(ap + ks * 32);
    }

    // lane-local derived threshold slack + dequant scale
    float dlt, inv2s, rmin = 1e30f;
    {
        float mx = __uint_as_float(*maxx), mc = __uint_as_float(*maxc);
        float dx = mx * (1.f / 254.f), dc = mc * (1.f / 254.f);
        float xr = xx[myrow], cm = __uint_as_float(*cbn_max);
        float var = (xr * dc * dc + cm * dx * dx) * (1.f / 3.f);
        dlt = 16.f * sqrtf(var) + 512.f * dx * dc + 0.01f;
        inv2s = 2.f * (mx * mc) * (1.f / 16129.f);      // 2/(sx*sc)
    }

    __syncthreads();            // cbn_fs visible; vmcnt drained to 0 (prologue)

    STAGE2(0, 0);               // 4 issues/thread outstanding

    // 6 candidate slots (registers, static indexing): g=1e30 means empty
    float g0 = 1e30f, g1 = 1e30f, g2 = 1e30f, g3 = 1e30f, g4 = 1e30f, g5 = 1e30f;
    u32   s0 = 0,     s1 = 0,     s2 = 0,     s3 = 0,     s4 = 0,     s5 = 0;

// per-tile epilogue + candidate insert (register-only, 1 shfl)
#define EPI(accv, tile_) do { \
        int _t = (tile_); \
        float cbnv[16]; \
        _Pragma("unroll") \
        for (int _q = 0; _q < 4; ++_q) \
            *reinterpret_cast<float4*>(&cbnv[_q * 4]) = \
                *reinterpret_cast<const float4*>(&cbn_fs[_t * 32 + kh * 16 + _q * 4]); \
        float gv[16], _m = 1e30f; \
        _Pragma("unroll") \
        for (int _r = 0; _r < 16; ++_r) { \
            gv[_r] = fmaf(-inv2s, (float)(accv)[_r], cbnv[_r]); \
            _m = fminf(_m, gv[_r]); \
        } \
        _m = fminf(_m, __shfl_xor(_m, 32, 64)); \
        rmin = fminf(rmin, _m); \
        float _thr = rmin + dlt; \
        _Pragma("unroll") \
        for (int _r = 0; _r < 16; ++_r) { \
            if (gv[_r] <= _thr) { \
                u32 _code = (u32)(_t * 32 + (_r & 3) + 8 * (_r >> 2) + 4 * kh); \
                float _mg = g0; int _mi = 0; \
                if (g1 > _mg) { _mg = g1; _mi = 1; } \
                if (g2 > _mg) { _mg = g2; _mi = 2; } \
                if (g3 > _mg) { _mg = g3; _mi = 3; } \
                if (g4 > _mg) { _mg = g4; _mi = 4; } \
                if (g5 > _mg) { _mg = g5; _mi = 5; } \
                if (_mg > _thr) { \
                    if      (_mi == 0) { g0 = gv[_r]; s0 = _code; } \
                    else if (_mi == 1) { g1 = gv[_r]; s1 = _code; } \
                    else if (_mi == 2) { g2 = gv[_r]; s2 = _code; } \
                    else if (_mi == 3) { g3 = gv[_r]; s3 = _code; } \
                    else if (_mi == 4) { g4 = gv[_r]; s4 = _code; } \
                    else               { g5 = gv[_r]; s5 = _code; } \
                } else { \
                    exact_rerank(X, CB, xx, cbn, myrow, (int)_code, best); \
                } \
            } \
        } \
    } while (0)

    for (int s = 0; s < 64; ++s) {          // 64 steps x 2 tiles, 1 barrier each
        asm volatile("s_waitcnt vmcnt(0)" ::: "memory");   // stage(s) landed
        __builtin_amdgcn_sched_barrier(0);
        __builtin_amdgcn_s_barrier();       // all loads landed + buf[(s+1)&1] free
        __builtin_amdgcn_sched_barrier(0);

        STAGE2((s + 1) & 63, (s + 1) & 1);  // issue next pair FIRST

        i32x16 aA = {}, aB = {};
        const signed char* Bt = &Bs[s & 1][0];
        #pragma unroll
        for (int ks = 0; ks < 8; ++ks) {            // two independent chains
            i32x4 cfA = *reinterpret_cast<const i32x4*>(&Bt[ks * 1024 + lane * 16]);
            i32x4 cfB = *reinterpret_cast<const i32x4*>(&Bt[8192 + ks * 1024 + lane * 16]);
            aA = __builtin_amdgcn_mfma_i32_32x32x32_i8(cfA, af[ks], aA, 0, 0, 0);
            aB = __builtin_amdgcn_mfma_i32_32x32x32_i8(cfB, af[ks], aB, 0, 0, 0);
        }

        EPI(aA, s * 2);                     // register-only; overlaps stage flight
        EPI(aB, s * 2 + 1);
    }

    // post-loop: exact fp32 rerank of slots still within the FINAL window
    float thrF = rmin + dlt;
    if (g0 <= thrF) exact_rerank(X, CB, xx, cbn, myrow, (int)s0, best);
    if (g1 <= thrF) exact_rerank(X, CB, xx, cbn, myrow, (int)s1, best);
    if (g2 <= thrF) exact_rerank(X, CB, xx, cbn, myrow, (int)s2, best);
    if (g3 <= thrF) exact_rerank(X, CB, xx, cbn, myrow, (int)s3, best);
    if (g4 <= thrF) exact_rerank(X, CB, xx, cbn, myrow, (int)s4, best);
    if (g5 <= thrF) exact_rerank(X, CB, xx, cbn, myrow, (int)s5, best);
#undef EPI
#undef STAGE2
}

// ---------- kernel 4: gather e, Householder STE ----------
__global__ __launch_bounds__(256) void k_epilogue(const float* __restrict__ X,
                                                  const float* __restrict__ CB,
                                                  const u64* __restrict__ best,
                                                  float* __restrict__ Eout,
                                                  float* __restrict__ Sout) {
    int r    = blockIdx.x * 4 + (threadIdx.x >> 6);
    int lane = threadIdx.x & 63;
    int idx  = (int)(best[r] & 0xffffffffull);

    float4 xv = *reinterpret_cast<const float4*>(X  + (size_t)r   * COLS + lane * 4);
    float4 ev = *reinterpret_cast<const float4*>(CB + (size_t)idx * COLS + lane * 4);

    float xn2 = wave_sum(dot4(xv, xv));
    float en2 = wave_sum(dot4(ev, ev));
    float xn = sqrtf(xn2), en = sqrtf(en2);
    float invx = 1.f / fmaxf(xn, EPSF);
    float inve = 1.f / fmaxf(en, EPSF);

    float4 xd, ed, sd0;
    xd.x = xv.x*invx; xd.y = xv.y*invx; xd.z = xv.z*invx; xd.w = xv.w*invx;
    ed.x = ev.x*inve; ed.y = ev.y*inve; ed.z = ev.z*inve; ed.w = ev.w*inve;
    sd0.x = xd.x+ed.x; sd0.y = xd.y+ed.y; sd0.z = xd.z+ed.z; sd0.w = xd.w+ed.w;

    float sdn2 = wave_sum(dot4(sd0, sd0));
    float p1   = wave_sum(dot4(sd0, xv));
    float p2   = wave_sum(dot4(xd,  xv));
    float invs = 1.f / fmaxf(sqrtf(sdn2), EPSF);

    float csd = -2.f * invs * invs * p1;
    float ced =  2.f * p2;
    float4 rr;
    rr.x = fmaf(csd, sd0.x, fmaf(ced, ed.x, xv.x));
    rr.y = fmaf(csd, sd0.y, fmaf(ced, ed.y, xv.y));
    rr.z = fmaf(csd, sd0.z, fmaf(ced, ed.z, xv.z));
    rr.w = fmaf(csd, sd0.w, fmaf(ced, ed.w, xv.w));
    float sc = en * invx;
    float4 sv; sv.x = rr.x*sc; sv.y = rr.y*sc; sv.z = rr.z*sc; sv.w = rr.w*sc;

    *reinterpret_cast<float4*>(Eout + (size_t)r * COLS + lane * 4) = ev;
    *reinterpret_cast<float4*>(Sout + (size_t)r * COLS + lane * 4) = sv;
}

// ---------- launcher ----------
extern "C" void kernel_launch(void* const* d_in, const int* in_sizes, int n_in,
                              void* d_out, int out_size, void* d_ws, size_t ws_size,
                              hipStream_t stream) {
    const float* x  = (const float*)d_in[0];
    const float* fc = (const float*)d_in[1];
    const float* Wi = (const float*)d_in[2];
    const float* Wo = (const float*)d_in[3];

    // ws layout (~5 MB)
    char* ws = (char*)d_ws;
    u64*   best    = (u64*)ws;                            ws += (size_t)ROWS * 8;
    float* CBws    = (float*)ws;                          ws += (size_t)Nn * COLS * 4;
    float* cbn     = (float*)ws;                          ws += (size_t)Nn * 4;
    float* cbn_f   = (float*)ws;                          ws += (size_t)Nn * 4;
    float* xx      = (float*)ws;                          ws += (size_t)ROWS * 4;
    u32*   cbn_max = (u32*)ws;                            ws += 4;
    u32*   maxx    = (u32*)ws;                            ws += 4;
    u32*   maxc    = (u32*)ws;

    // i8 copies live in d_out (128 MiB), only overwritten by k_epilogue at the
    // very end: Xq = 16 MiB at offset 0, CBq = 1 MiB at offset 64 MiB.
    signed char* Xq  = (signed char*)d_out;
    signed char* CBq = (signed char*)((char*)d_out + (64u << 20));

    float* Eout = (float*)d_out;
    float* Sout = Eout + (size_t)ROWS * COLS;

    k_init<<<1, 64, 0, stream>>>(cbn_max, maxx, maxc);
    k_prep<<<ROWS / 4, 256, 0, stream>>>(x, xx, best, maxx);
    k_codebook<<<Nn, 256, 0, stream>>>(fc, Wi, Wo, CBws, cbn, cbn_f, cbn_max, maxc);
    k_quantx<<<ROWS / 4, 256, 0, stream>>>(x, Xq, maxx);
    k_quantcb<<<Nn, 256, 0, stream>>>(CBws, CBq, maxc);
    k_screen_fused<<<ROWS / 128, 256, 0, stream>>>(Xq, CBq, x, CBws, cbn, cbn_f, xx,
                                                   best, cbn_max, maxx, maxc);
    k_epilogue<<<ROWS / 4, 256, 0, stream>>>(x, CBws, best, Eout, Sout);
}

// Round 20
// 722.794 us; speedup vs baseline: 2.1334x; 2.1334x over previous
//
#include <hip/hip_runtime.h>
#include <hip/hip_bf16.h>
#include <stdint.h>

// Problem dims (fixed by reference)
#define Bq    8192
#define Hh    8
#define Dd    16
#define Kk    16
#define Nn    4096
#define DFf   16
#define ROWS  (Bq*Hh)          // 65536
#define COLS  (Dd*Kk)          // 256
#define EPSF  1e-6f

typedef unsigned long long u64;
typedef unsigned int u32;
typedef __attribute__((ext_vector_type(4)))  int i32x4;
typedef __attribute__((ext_vector_type(16))) int i32x16;

// async global->LDS, 16B per lane; LDS dest = wave-uniform base + lane*16
#define GLOAD_LDS(g, l) __builtin_amdgcn_global_load_lds( \
    (const __attribute__((address_space(1))) u32*)(g), \
    (__attribute__((address_space(3))) u32*)(l), 16, 0, 0)

// ---------- helpers ----------
__device__ __forceinline__ float dot4(float4 a, float4 b) {
    return fmaf(a.x, b.x, fmaf(a.y, b.y, fmaf(a.z, b.z, a.w * b.w)));
}
__device__ __forceinline__ float wave_sum(float v) {
    #pragma unroll
    for (int m = 32; m > 0; m >>= 1) v += __shfl_xor(v, m, 64);
    return v;
}
__device__ __forceinline__ float wave_max(float v) {
    #pragma unroll
    for (int m = 32; m > 0; m >>= 1) v = fmaxf(v, __shfl_xor(v, m, 64));
    return v;
}
__device__ __forceinline__ u32 f32_sortable(float f) {
    u32 u = __float_as_uint(f);
    return (u & 0x80000000u) ? ~u : (u | 0x80000000u);
}
__device__ __forceinline__ int q8(float v, float s) {
    int q = (int)__builtin_rintf(v * s);          // RNE
    return q > 127 ? 127 : (q < -127 ? -127 : q);
}
// exact fp32 rerank, R2's accepted expression tree (sequential fmaf over 64 float4s)
__device__ __forceinline__ void exact_rerank(const float* __restrict__ X,
                                             const float* __restrict__ CB,
                                             const float* __restrict__ xx,
                                             const float* __restrict__ cbn,
                                             int row, int col,
                                             u64* __restrict__ best) {
    const float4* xp = (const float4*)(X + (size_t)row * COLS);
    const float4* cp = (const float4*)(CB + (size_t)col * COLS);
    float d = 0.f;
    #pragma unroll 8
    for (int q = 0; q < 64; ++q) {
        float4 a = xp[q], b = cp[q];
        d = fmaf(a.x, b.x, d); d = fmaf(a.y, b.y, d);
        d = fmaf(a.z, b.z, d); d = fmaf(a.w, b.w, d);
    }
    float d2e = fmaf(-2.f, d, xx[row]) + cbn[col];
    u64 pk = ((u64)f32_sortable(d2e) << 32) | (u32)col;
    atomicMin(&best[row], pk);
}

// ---------- kernel 0: xx[r], per-block max|x| (NO atomics), init best ----------
__global__ __launch_bounds__(256) void k_prep(const float* __restrict__ X,
                                              float* __restrict__ xx,
                                              u64* __restrict__ best,
                                              float* __restrict__ xmaxarr) {
    __shared__ float wmax[4];
    int r    = blockIdx.x * 4 + (threadIdx.x >> 6);
    int lane = threadIdx.x & 63;
    float4 v = *reinterpret_cast<const float4*>(X + (size_t)r * COLS + lane * 4);
    float s = wave_sum(v.x*v.x + v.y*v.y + v.z*v.z + v.w*v.w);
    float am = wave_max(fmaxf(fmaxf(fabsf(v.x), fabsf(v.y)),
                              fmaxf(fabsf(v.z), fabsf(v.w))));
    if (lane == 0) { xx[r] = s; best[r] = ~0ull; wmax[threadIdx.x >> 6] = am; }
    __syncthreads();
    if (threadIdx.x == 0)
        xmaxarr[blockIdx.x] = fmaxf(fmaxf(wmax[0], wmax[1]), fmaxf(wmax[2], wmax[3]));
}

// ---------- kernel 1: codebook fp32 + cbn + acc-order cbn_f + per-code max|c| ----------
__global__ __launch_bounds__(256) void k_codebook(const float* __restrict__ fc,
                                                  const float* __restrict__ Wi,
                                                  const float* __restrict__ Wo,
                                                  float* __restrict__ CB,
                                                  float* __restrict__ cbn,
                                                  float* __restrict__ cbn_f,
                                                  float* __restrict__ camax) {
    int n = blockIdx.x, tid = threadIdx.x;
    int o = tid >> 4, k = tid & 15;
    __shared__ float fcs[256], wis[256], wos[256], hs[256], sq[256], am[256];
    fcs[tid] = fc[(size_t)n * 256 + tid];
    wis[tid] = Wi[tid];
    wos[tid] = Wo[tid];
    __syncthreads();
    float hp = 0.f;
    #pragma unroll
    for (int i = 0; i < 16; ++i) hp = fmaf(wis[o*16 + i], fcs[i*16 + k], hp);
    hs[tid] = hp;
    __syncthreads();
    float h0 = hs[o * 16];
    float x3 = h0 * h0 * h0;
    float inner = 0.7978845608028654f * fmaf(0.044715f, x3, h0);
    float g = 0.5f * h0 * (1.f + tanhf(inner));
    float hg = hp * g;
    __syncthreads();
    hs[tid] = hg;
    __syncthreads();
    float cv = 0.f;
    #pragma unroll
    for (int i = 0; i < 16; ++i) cv = fmaf(wos[o*16 + i], hs[i*16 + k], cv);
    CB[(size_t)n * 256 + tid] = cv;
    sq[tid] = cv * cv;
    am[tid] = fabsf(cv);
    __syncthreads();
    #pragma unroll
    for (int st = 128; st > 0; st >>= 1) {
        if (tid < st) { sq[tid] += sq[tid + st]; am[tid] = fmaxf(am[tid], am[tid + st]); }
        __syncthreads();
    }
    if (tid == 0) {
        cbn[n] = sq[0];
        camax[n] = am[0];
        int tile = n >> 5, c = n & 31;
        int h = (c >> 2) & 1, r = (c & 3) | ((c >> 3) << 2);
        cbn_f[tile * 32 + h * 16 + r] = sq[0];
    }
}

// ---------- kernel 1b: single-block reduction -> maxx, maxc, cbn_max ----------
__global__ __launch_bounds__(256) void k_reduce(const float* __restrict__ xmaxarr,
                                                const float* __restrict__ camax,
                                                const float* __restrict__ cbn,
                                                u32* __restrict__ maxx,
                                                u32* __restrict__ maxc,
                                                u32* __restrict__ cbn_max) {
    __shared__ float sx[256], sc[256], sn[256];
    int tid = threadIdx.x;
    float mx = 0.f, mc = 0.f, cm = 0.f;
    for (int i = tid; i < 16384; i += 256) mx = fmaxf(mx, xmaxarr[i]);
    for (int i = tid; i < Nn; i += 256) { mc = fmaxf(mc, camax[i]); cm = fmaxf(cm, cbn[i]); }
    sx[tid] = mx; sc[tid] = mc; sn[tid] = cm;
    __syncthreads();
    #pragma unroll
    for (int st = 128; st > 0; st >>= 1) {
        if (tid < st) {
            sx[tid] = fmaxf(sx[tid], sx[tid + st]);
            sc[tid] = fmaxf(sc[tid], sc[tid + st]);
            sn[tid] = fmaxf(sn[tid], sn[tid + st]);
        }
        __syncthreads();
    }
    if (tid == 0) {
        *maxx    = __float_as_uint(sx[0]);
        *maxc    = __float_as_uint(sc[0]);
        *cbn_max = __float_as_uint(sn[0]);
    }
}

// ---------- kernel 2a: quantize X -> i8 (row-major) ----------
__global__ __launch_bounds__(256) void k_quantx(const float* __restrict__ X,
                                                signed char* __restrict__ Xq,
                                                const u32* __restrict__ maxx) {
    int r    = blockIdx.x * 4 + (threadIdx.x >> 6);
    int lane = threadIdx.x & 63;
    float sx = 127.f / __uint_as_float(*maxx);
    float4 v = *reinterpret_cast<const float4*>(X + (size_t)r * COLS + lane * 4);
    u32 p = (u32)(u32(q8(v.x, sx)) & 0xff)
          | ((u32)(q8(v.y, sx) & 0xff) << 8)
          | ((u32)(q8(v.z, sx) & 0xff) << 16)
          | ((u32)(q8(v.w, sx) & 0xff) << 24);
    *reinterpret_cast<u32*>(Xq + (size_t)r * COLS + lane * 4) = p;
}

// ---------- kernel 2b: quantize CB -> i8 in 32x32x32 FRAGMENT order ----------
// CBq layout: per 32-code tile (8 KB), frag ks (0..7) is 1 KB:
// lane l = h*32 + c holds 16 i8 of code (tile*32+c), k = ks*32 + h*16 .. +15.
__global__ __launch_bounds__(256) void k_quantcb(const float* __restrict__ CB,
                                                 signed char* __restrict__ CBq,
                                                 const u32* __restrict__ maxc) {
    int n = blockIdx.x, tid = threadIdx.x;
    __shared__ signed char qs[256];
    float sc = 127.f / __uint_as_float(*maxc);
    qs[tid] = (signed char)q8(CB[(size_t)n * 256 + tid], sc);
    __syncthreads();
    if (tid < 16) {
        int ks = tid >> 1, h = tid & 1;
        int tile = n >> 5, c = n & 31;
        size_t off = (size_t)tile * 8192 + ks * 1024 + (h * 32 + c) * 16;
        *reinterpret_cast<uint4*>(CBq + off) =
            *reinterpret_cast<const uint4*>(&qs[tid * 16]);
    }
}

// ---------- kernel 3: swapped-operand i8 32x32x32 screen (R19, unchanged) ----------
__global__ __launch_bounds__(256, 2) void k_screen_fused(
        const signed char* __restrict__ Xq,
        const signed char* __restrict__ CBq,
        const float* __restrict__ X,
        const float* __restrict__ CB,
        const float* __restrict__ cbn,
        const float* __restrict__ cbn_f,
        const float* __restrict__ xx,
        u64* __restrict__ best,
        const u32* __restrict__ cbn_max,
        const u32* __restrict__ maxx,
        const u32* __restrict__ maxc) {
    __shared__ __align__(16) signed char Bs[2][16384];  // 2 x (pair of 8KB tiles)
    __shared__ float cbn_fs[Nn];                        // 16 KB, acc-order

    const int tid  = threadIdx.x;
    const int lane = tid & 63;
    const int w    = tid >> 6;           // wave 0..3
    const int cl   = lane & 31;          // this lane's x-row (D col)
    const int kh   = lane >> 5;          // k-half / code-half
    const int bmBase = blockIdx.x * 128; // 32 x-rows per wave
    const int myrow  = bmBase + w * 32 + cl;

// stage tile PAIR P (tiles 2P, 2P+1) into Bs[buf]: 4 gloads/thread
#define STAGE2(P_, buf) do { \
        int _P = (P_); \
        _Pragma("unroll") \
        for (int _i = 0; _i < 4; ++_i) { \
            int _half = _i >> 1; \
            int _f = (_i & 1) * 4 + w; \
            const signed char* _g = CBq + (size_t)(_P * 2 + _half) * 8192 \
                                  + _f * 1024 + lane * 16; \
            GLOAD_LDS(_g, &Bs[(buf)][_half * 8192 + _f * 1024]); \
        } \
    } while (0)

    // cbn_f -> LDS (acc-order, all 4096 codes)
    #pragma unroll
    for (int j = 0; j < 4; ++j)
        *reinterpret_cast<float4*>(&cbn_fs[tid * 16 + j * 4]) =
            *reinterpret_cast<const float4*>(&cbn_f[tid * 16 + j * 4]);

    // X fragments (B-operand): af[ks], lane holds x-row myrow,
    // k = ks*32 + kh*16 .. +15 (16 i8 = 4 regs)
    i32x4 af[8];
    {
        const signed char* ap = Xq + ((size_t)myrow << 8) + kh * 16;
        #pragma unroll
        for (int ks = 0; ks < 8; ++ks)
            af[ks] = *reinterpret_cast<const i32x4*>(ap + ks * 32);
    }

    // lane-local derived threshold slack + dequant scale
    float dlt, inv2s, rmin = 1e30f;
    {
        float mx = __uint_as_float(*maxx), mc = __uint_as_float(*maxc);
        float dx = mx * (1.f / 254.f), dc = mc * (1.f / 254.f);
        float xr = xx[myrow], cm = __uint_as_float(*cbn_max);
        float var = (xr * dc * dc + cm * dx * dx) * (1.f / 3.f);
        dlt = 16.f * sqrtf(var) + 512.f * dx * dc + 0.01f;
        inv2s = 2.f * (mx * mc) * (1.f / 16129.f);      // 2/(sx*sc)
    }

    __syncthreads();            // cbn_fs visible; vmcnt drained to 0 (prologue)

    STAGE2(0, 0);               // 4 issues/thread outstanding

    // 6 candidate slots (registers, static indexing): g=1e30 means empty
    float g0 = 1e30f, g1 = 1e30f, g2 = 1e30f, g3 = 1e30f, g4 = 1e30f, g5 = 1e30f;
    u32   s0 = 0,     s1 = 0,     s2 = 0,     s3 = 0,     s4 = 0,     s5 = 0;

// per-tile epilogue + candidate insert (register-only, 1 shfl)
#define EPI(accv, tile_) do { \
        int _t = (tile_); \
        float cbnv[16]; \
        _Pragma("unroll") \
        for (int _q = 0; _q < 4; ++_q) \
            *reinterpret_cast<float4*>(&cbnv[_q * 4]) = \
                *reinterpret_cast<const float4*>(&cbn_fs[_t * 32 + kh * 16 + _q * 4]); \
        float gv[16], _m = 1e30f; \
        _Pragma("unroll") \
        for (int _r = 0; _r < 16; ++_r) { \
            gv[_r] = fmaf(-inv2s, (float)(accv)[_r], cbnv[_r]); \
            _m = fminf(_m, gv[_r]); \
        } \
        _m = fminf(_m, __shfl_xor(_m, 32, 64)); \
        rmin = fminf(rmin, _m); \
        float _thr = rmin + dlt; \
        _Pragma("unroll") \
        for (int _r = 0; _r < 16; ++_r) { \
            if (gv[_r] <= _thr) { \
                u32 _code = (u32)(_t * 32 + (_r & 3) + 8 * (_r >> 2) + 4 * kh); \
                float _mg = g0; int _mi = 0; \
                if (g1 > _mg) { _mg = g1; _mi = 1; } \
                if (g2 > _mg) { _mg = g2; _mi = 2; } \
                if (g3 > _mg) { _mg = g3; _mi = 3; } \
                if (g4 > _mg) { _mg = g4; _mi = 4; } \
                if (g5 > _mg) { _mg = g5; _mi = 5; } \
                if (_mg > _thr) { \
                    if      (_mi == 0) { g0 = gv[_r]; s0 = _code; } \
                    else if (_mi == 1) { g1 = gv[_r]; s1 = _code; } \
                    else if (_mi == 2) { g2 = gv[_r]; s2 = _code; } \
                    else if (_mi == 3) { g3 = gv[_r]; s3 = _code; } \
                    else if (_mi == 4) { g4 = gv[_r]; s4 = _code; } \
                    else               { g5 = gv[_r]; s5 = _code; } \
                } else { \
                    exact_rerank(X, CB, xx, cbn, myrow, (int)_code, best); \
                } \
            } \
        } \
    } while (0)

    for (int s = 0; s < 64; ++s) {          // 64 steps x 2 tiles, 1 barrier each
        asm volatile("s_waitcnt vmcnt(0)" ::: "memory");   // stage(s) landed
        __builtin_amdgcn_sched_barrier(0);
        __builtin_amdgcn_s_barrier();       // all loads landed + buf[(s+1)&1] free
        __builtin_amdgcn_sched_barrier(0);

        STAGE2((s + 1) & 63, (s + 1) & 1);  // issue next pair FIRST

        i32x16 aA = {}, aB = {};
        const signed char* Bt = &Bs[s & 1][0];
        #pragma unroll
        for (int ks = 0; ks < 8; ++ks) {            // two independent chains
            i32x4 cfA = *reinterpret_cast<const i32x4*>(&Bt[ks * 1024 + lane * 16]);
            i32x4 cfB = *reinterpret_cast<const i32x4*>(&Bt[8192 + ks * 1024 + lane * 16]);
            aA = __builtin_amdgcn_mfma_i32_32x32x32_i8(cfA, af[ks], aA, 0, 0, 0);
            aB = __builtin_amdgcn_mfma_i32_32x32x32_i8(cfB, af[ks], aB, 0, 0, 0);
        }

        EPI(aA, s * 2);                     // register-only; overlaps stage flight
        EPI(aB, s * 2 + 1);
    }

    // post-loop: exact fp32 rerank of slots still within the FINAL window
    float thrF = rmin + dlt;
    if (g0 <= thrF) exact_rerank(X, CB, xx, cbn, myrow, (int)s0, best);
    if (g1 <= thrF) exact_rerank(X, CB, xx, cbn, myrow, (int)s1, best);
    if (g2 <= thrF) exact_rerank(X, CB, xx, cbn, myrow, (int)s2, best);
    if (g3 <= thrF) exact_rerank(X, CB, xx, cbn, myrow, (int)s3, best);
    if (g4 <= thrF) exact_rerank(X, CB, xx, cbn, myrow, (int)s4, best);
    if (g5 <= thrF) exact_rerank(X, CB, xx, cbn, myrow, (int)s5, best);
#undef EPI
#undef STAGE2
}

// ---------- kernel 4: gather e, Householder STE ----------
__global__ __launch_bounds__(256) void k_epilogue(const float* __restrict__ X,
                                                  const float* __restrict__ CB,
                                                  const u64* __restrict__ best,
                                                  float* __restrict__ Eout,
                                                  float* __restrict__ Sout) {
    int r    = blockIdx.x * 4 + (threadIdx.x >> 6);
    int lane = threadIdx.x & 63;
    int idx  = (int)(best[r] & 0xffffffffull);

    float4 xv = *reinterpret_cast<const float4*>(X  + (size_t)r   * COLS + lane * 4);
    float4 ev = *reinterpret_cast<const float4*>(CB + (size_t)idx * COLS + lane * 4);

    float xn2 = wave_sum(dot4(xv, xv));
    float en2 = wave_sum(dot4(ev, ev));
    float xn = sqrtf(xn2), en = sqrtf(en2);
    float invx = 1.f / fmaxf(xn, EPSF);
    float inve = 1.f / fmaxf(en, EPSF);

    float4 xd, ed, sd0;
    xd.x = xv.x*invx; xd.y = xv.y*invx; xd.z = xv.z*invx; xd.w = xv.w*invx;
    ed.x = ev.x*inve; ed.y = ev.y*inve; ed.z = ev.z*inve; ed.w = ev.w*inve;
    sd0.x = xd.x+ed.x; sd0.y = xd.y+ed.y; sd0.z = xd.z+ed.z; sd0.w = xd.w+ed.w;

    float sdn2 = wave_sum(dot4(sd0, sd0));
    float p1   = wave_sum(dot4(sd0, xv));
    float p2   = wave_sum(dot4(xd,  xv));
    float invs = 1.f / fmaxf(sqrtf(sdn2), EPSF);

    float csd = -2.f * invs * invs * p1;
    float ced =  2.f * p2;
    float4 rr;
    rr.x = fmaf(csd, sd0.x, fmaf(ced, ed.x, xv.x));
    rr.y = fmaf(csd, sd0.y, fmaf(ced, ed.y, xv.y));
    rr.z = fmaf(csd, sd0.z, fmaf(ced, ed.z, xv.z));
    rr.w = fmaf(csd, sd0.w, fmaf(ced, ed.w, xv.w));
    float sc = en * invx;
    float4 sv; sv.x = rr.x*sc; sv.y = rr.y*sc; sv.z = rr.z*sc; sv.w = rr.w*sc;

    *reinterpret_cast<float4*>(Eout + (size_t)r * COLS + lane * 4) = ev;
    *reinterpret_cast<float4*>(Sout + (size_t)r * COLS + lane * 4) = sv;
}

// ---------- launcher ----------
extern "C" void kernel_launch(void* const* d_in, const int* in_sizes, int n_in,
                              void* d_out, int out_size, void* d_ws, size_t ws_size,
                              hipStream_t stream) {
    const float* x  = (const float*)d_in[0];
    const float* fc = (const float*)d_in[1];
    const float* Wi = (const float*)d_in[2];
    const float* Wo = (const float*)d_in[3];

    // ws layout (~5 MB)
    char* ws = (char*)d_ws;
    u64*   best    = (u64*)ws;                            ws += (size_t)ROWS * 8;
    float* CBws    = (float*)ws;                          ws += (size_t)Nn * COLS * 4;
    float* cbn     = (float*)ws;                          ws += (size_t)Nn * 4;
    float* cbn_f   = (float*)ws;                          ws += (size_t)Nn * 4;
    float* xx      = (float*)ws;                          ws += (size_t)ROWS * 4;
    float* xmaxarr = (float*)ws;                          ws += (size_t)16384 * 4;
    float* camax   = (float*)ws;                          ws += (size_t)Nn * 4;
    u32*   cbn_max = (u32*)ws;                            ws += 4;
    u32*   maxx    = (u32*)ws;                            ws += 4;
    u32*   maxc    = (u32*)ws;

    // i8 copies live in d_out (128 MiB), only overwritten by k_epilogue at the
    // very end: Xq = 16 MiB at offset 0, CBq = 1 MiB at offset 64 MiB.
    signed char* Xq  = (signed char*)d_out;
    signed char* CBq = (signed char*)((char*)d_out + (64u << 20));

    float* Eout = (float*)d_out;
    float* Sout = Eout + (size_t)ROWS * COLS;

    k_prep<<<ROWS / 4, 256, 0, stream>>>(x, xx, best, xmaxarr);
    k_codebook<<<Nn, 256, 0, stream>>>(fc, Wi, Wo, CBws, cbn, cbn_f, camax);
    k_reduce<<<1, 256, 0, stream>>>(xmaxarr, camax, cbn, maxx, maxc, cbn_max);
    k_quantx<<<ROWS / 4, 256, 0, stream>>>(x, Xq, maxx);
    k_quantcb<<<Nn, 256, 0, stream>>>(CBws, CBq, maxc);
    k_screen_fused<<<ROWS / 128, 256, 0, stream>>>(Xq, CBq, x, CBws, cbn, cbn_f, xx,
                                                   best, cbn_max, maxx, maxc);
    k_epilogue<<<ROWS / 4, 256, 0, stream>>>(x, CBws, best, Eout, Sout);
}

// Round 21
// 422.781 us; speedup vs baseline: 3.6474x; 1.7096x over previous
//
#include <hip/hip_runtime.h>
#include <hip/hip_bf16.h>
#include <stdint.h>

// Problem dims (fixed by reference)
#define Bq    8192
#define Hh    8
#define Dd    16
#define Kk    16
#define Nn    4096
#define DFf   16
#define ROWS  (Bq*Hh)          // 65536
#define COLS  (Dd*Kk)          // 256
#define EPSF  1e-6f

typedef unsigned long long u64;
typedef unsigned int u32;
typedef __attribute__((ext_vector_type(8)))  short bf16x8;
typedef __attribute__((ext_vector_type(16))) float f32x16;

// async global->LDS, 16B per lane; LDS dest = wave-uniform base + lane*16
#define GLOAD_LDS(g, l) __builtin_amdgcn_global_load_lds( \
    (const __attribute__((address_space(1))) u32*)(g), \
    (__attribute__((address_space(3))) u32*)(l), 16, 0, 0)

// ---------- helpers ----------
__device__ __forceinline__ float dot4(float4 a, float4 b) {
    return fmaf(a.x, b.x, fmaf(a.y, b.y, fmaf(a.z, b.z, a.w * b.w)));
}
__device__ __forceinline__ float wave_sum(float v) {
    #pragma unroll
    for (int m = 32; m > 0; m >>= 1) v += __shfl_xor(v, m, 64);
    return v;
}
__device__ __forceinline__ u32 f32_sortable(float f) {
    u32 u = __float_as_uint(f);
    return (u & 0x80000000u) ? ~u : (u | 0x80000000u);
}
// pack 2 floats -> 2 bf16 (RNE); low 16 bits = a
__device__ __forceinline__ u32 pk2(float a, float b) {
    union { __hip_bfloat162 h; u32 u; } v;
    v.h = __float22bfloat162_rn(make_float2(a, b));
    return v.u;
}
// exact fp32 rerank, R2's accepted expression tree (sequential fmaf over 64 float4s)
__device__ __forceinline__ void exact_rerank(const float* __restrict__ X,
                                             const float* __restrict__ CB,
                                             const float* __restrict__ xx,
                                             const float* __restrict__ cbn,
                                             int row, int col,
                                             u64* __restrict__ best) {
    const float4* xp = (const float4*)(X + (size_t)row * COLS);
    const float4* cp = (const float4*)(CB + (size_t)col * COLS);
    float d = 0.f;
    #pragma unroll 8
    for (int q = 0; q < 64; ++q) {
        float4 a = xp[q], b = cp[q];
        d = fmaf(a.x, b.x, d); d = fmaf(a.y, b.y, d);
        d = fmaf(a.z, b.z, d); d = fmaf(a.w, b.w, d);
    }
    float d2e = fmaf(-2.f, d, xx[row]) + cbn[col];
    u64 pk = ((u64)f32_sortable(d2e) << 32) | (u32)col;
    atomicMin(&best[row], pk);
}

// ---------- kernel 0: xx[r], X->bf16 (row-major), init best ----------
__global__ __launch_bounds__(256) void k_prep(const float* __restrict__ X,
                                              short* __restrict__ Xh,
                                              float* __restrict__ xx,
                                              u64* __restrict__ best) {
    int r    = blockIdx.x * 4 + (threadIdx.x >> 6);
    int lane = threadIdx.x & 63;
    float4 v = *reinterpret_cast<const float4*>(X + (size_t)r * COLS + lane * 4);
    uint2 p; p.x = pk2(v.x, v.y); p.y = pk2(v.z, v.w);
    *reinterpret_cast<uint2*>(Xh + (size_t)r * COLS + lane * 4) = p;
    float s = wave_sum(v.x*v.x + v.y*v.y + v.z*v.z + v.w*v.w);
    if (lane == 0) { xx[r] = s; best[r] = ~0ull; }
}

// ---------- kernel 1: codebook fp32 + 32x32-FRAGMENT bf16 + cbn (+acc-order copy) ----------
// CBf layout (R10/R13, HW-verified): per 32-code tile (16 KB), frag f = kstep
// (0..15) is 1 KB: lane l = h*32 + c holds code row (tile*32 + c),
// k = kstep*16 + h*8 .. +8.  cbn_f = cbn permuted into acc order:
// cbn_f[tile*32 + h*16 + r] = cbn[tile*32 + crow(r,h)], crow = (r&3)+8*(r>>2)+4h.
// NO single-address atomics (R19 lesson): cbn_max computed by k_reduce_cbn.
__global__ __launch_bounds__(256) void k_codebook(const float* __restrict__ fc,
                                                  const float* __restrict__ Wi,
                                                  const float* __restrict__ Wo,
                                                  float* __restrict__ CB,
                                                  short* __restrict__ CBf,
                                                  float* __restrict__ cbn,
                                                  float* __restrict__ cbn_f) {
    int n = blockIdx.x, tid = threadIdx.x;
    int o = tid >> 4, k = tid & 15;
    __shared__ float fcs[256], wis[256], wos[256], hs[256], sq[256];
    __shared__ short cvs_sh[256];
    fcs[tid] = fc[(size_t)n * 256 + tid];
    wis[tid] = Wi[tid];
    wos[tid] = Wo[tid];
    __syncthreads();
    float hp = 0.f;
    #pragma unroll
    for (int i = 0; i < 16; ++i) hp = fmaf(wis[o*16 + i], fcs[i*16 + k], hp);
    hs[tid] = hp;
    __syncthreads();
    float h0 = hs[o * 16];
    float x3 = h0 * h0 * h0;
    float inner = 0.7978845608028654f * fmaf(0.044715f, x3, h0);
    float g = 0.5f * h0 * (1.f + tanhf(inner));
    float hg = hp * g;
    __syncthreads();
    hs[tid] = hg;
    __syncthreads();
    float cv = 0.f;
    #pragma unroll
    for (int i = 0; i < 16; ++i) cv = fmaf(wos[o*16 + i], hs[i*16 + k], cv);
    CB[(size_t)n * 256 + tid] = cv;
    { union { __hip_bfloat16 h; short s; } c; c.h = __float2bfloat16(cv);
      cvs_sh[tid] = c.s; }
    sq[tid] = cv * cv;
    __syncthreads();
    #pragma unroll
    for (int st = 128; st > 0; st >>= 1) {
        if (tid < st) sq[tid] += sq[tid + st];
        __syncthreads();
    }
    if (tid == 0) {
        cbn[n] = sq[0];
        int tile = n >> 5, c = n & 31;
        int h = (c >> 2) & 1, r = (c & 3) | ((c >> 3) << 2);
        cbn_f[tile * 32 + h * 16 + r] = sq[0];
    }
    // swizzled write: 32 chunks of 8 bf16 -> 32x32-fragment slots
    if (tid < 32) {
        int kc = tid;                      // 8-short chunk, k = kc*8
        int tile = n >> 5, c = n & 31;
        int kstep = kc >> 1, h = kc & 1;
        size_t off = (size_t)tile * 8192 + kstep * 512 + h * 256 + c * 8;
        *reinterpret_cast<uint4*>(CBf + off) =
            *reinterpret_cast<const uint4*>(&cvs_sh[kc * 8]);
    }
}

// ---------- kernel 1b: single-block max(cbn) -> cbn_max (plain store) ----------
__global__ __launch_bounds__(256) void k_reduce_cbn(const float* __restrict__ cbn,
                                                    u32* __restrict__ cbn_max) {
    __shared__ float sn[256];
    int tid = threadIdx.x;
    float cm = 0.f;
    for (int i = tid; i < Nn; i += 256) cm = fmaxf(cm, cbn[i]);
    sn[tid] = cm;
    __syncthreads();
    #pragma unroll
    for (int st = 128; st > 0; st >>= 1) {
        if (tid < st) sn[tid] = fmaxf(sn[tid], sn[tid + st]);
        __syncthreads();
    }
    if (tid == 0) *cbn_max = __float_as_uint(sn[0]);
}

// ---------- kernel 2: swapped-operand 32x32 bf16 screen, 32KB LDS / 16 waves/CU ----------
// 1024 blocks x 256 threads: bm = bid>>1 (128 x-rows, 32/wave), half = bid&1
// (2048 codes = 64 tiles). Per-wave structure = R15/R16 (HW-verified): lane
// owns one x-row; mfma(code_frag, x_frag); register-only EPI + 1 shfl/tile;
// 6-slot stale-eviction candidates; bf16 dlt = 0.003*sqrt(xx*cbn_max)+0.01.
// WHY: R15-R17 pinned at 8 waves/CU (every pipe ~23%, latency-bound); R16's
// 80KB LDS allowed only 2 blocks/CU. Here LDS = 2x16KB buffers ONLY (cbn_f
// read from GLOBAL: 16KB L2-hot, 2 broadcast lines/step, hidden under MFMA;
// safe because the schedule waits vmcnt(0) each step). 32KB x 4 blocks +
// regs ~120<=128 -> 16 waves/CU. launch_bounds(256,3) caps ~170 (no spill;
// R18's (512,4)=128-cap mistake avoided). Single-barrier 2-phase schedule
// (R17-neutral): wait vmcnt(0); barrier; STAGE(t+1 -> other buf); 16
// ds_read_b128 + 16 MFMA; EPI. Partial-sweep safety (R11-proven): running
// rmin includes current tile -> true argmin + exact ties enter some block's
// set; exact fp32 rerank (R2 tree) + packed atomicMin(best) merges.
__global__ __launch_bounds__(256, 3) void k_screen_fused(
        const short* __restrict__ Xh,
        const short* __restrict__ CBf,
        const float* __restrict__ X,
        const float* __restrict__ CB,
        const float* __restrict__ cbn,
        const float* __restrict__ cbn_f,
        const float* __restrict__ xx,
        u64* __restrict__ best,
        const u32* __restrict__ cbn_max) {
    __shared__ __align__(16) short Bs[2][8192];   // 2 x 16 KB code tiles ONLY

    const int tid  = threadIdx.x;
    const int lane = tid & 63;
    const int w    = tid >> 6;           // wave 0..3
    const int cl   = lane & 31;          // this lane's x-row (D col)
    const int kh   = lane >> 5;          // k-half / code-half
    const int half = blockIdx.x & 1;     // codebook half
    const int tgBase = half * 64;        // first global tile of this half
    const int bmBase = (blockIdx.x >> 1) * 128;   // 32 x-rows per wave
    const int myrow  = bmBase + w * 32 + cl;

// stage GLOBAL tile tg into Bs[buf]: 4 gloads/thread
#define STAGE(tg_, buf) do { \
        int _t = (tg_); \
        _Pragma("unroll") \
        for (int _i = 0; _i < 4; ++_i) { \
            int _f = _i * 4 + w; \
            const short* _g = CBf + (size_t)_t * 8192 + _f * 512 + lane * 8; \
            GLOAD_LDS(_g, &Bs[(buf)][_f * 512]); \
        } \
    } while (0)

    // X fragments (B-operand): af[kstep], lane holds x-row myrow,
    // k = kstep*16 + kh*8 .. +8
    bf16x8 af[16];
    {
        const short* ap = Xh + ((size_t)myrow << 8) + kh * 8;
        #pragma unroll
        for (int ks = 0; ks < 16; ++ks)
            af[ks] = *reinterpret_cast<const bf16x8*>(ap + ks * 16);
    }

    // lane-local threshold slack (exact per-row, R16 formula)
    float dlt, rmin = 1e30f;
    {
        float xr = xx[myrow];
        dlt = fmaf(0.003f, sqrtf(xr * __uint_as_float(*cbn_max)), 0.01f);
    }

    STAGE(tgBase, 0);           // prologue: 4 issues/thread outstanding

    // 6 candidate slots (registers, static indexing): g=1e30 means empty
    float g0 = 1e30f, g1 = 1e30f, g2 = 1e30f, g3 = 1e30f, g4 = 1e30f, g5 = 1e30f;
    u32   s0 = 0,     s1 = 0,     s2 = 0,     s3 = 0,     s4 = 0,     s5 = 0;

    for (int t = 0; t < 64; ++t) {          // 64 single-tile steps, 1 barrier each
        asm volatile("s_waitcnt vmcnt(0)" ::: "memory");   // stage(t) landed
        __builtin_amdgcn_sched_barrier(0);
        __builtin_amdgcn_s_barrier();       // all loads landed + buf[(t+1)&1] free
        __builtin_amdgcn_sched_barrier(0);

        STAGE(tgBase + ((t + 1) & 63), (t + 1) & 1);  // next tile flies under compute

        // cbn values for this tile from GLOBAL (L2-hot, 2 broadcast lines)
        float cbnv[16];
        #pragma unroll
        for (int q = 0; q < 4; ++q)
            *reinterpret_cast<float4*>(&cbnv[q * 4]) =
                *reinterpret_cast<const float4*>(
                    &cbn_f[(tgBase + t) * 32 + kh * 16 + q * 4]);

        f32x16 acc;
        #pragma unroll
        for (int r = 0; r < 16; ++r) acc[r] = 0.f;

        const short* Bt = &Bs[t & 1][0];
        #pragma unroll
        for (int ks = 0; ks < 16; ++ks) {
            bf16x8 cf = *reinterpret_cast<const bf16x8*>(&Bt[ks * 512 + lane * 8]);
            acc = __builtin_amdgcn_mfma_f32_32x32x16_bf16(cf, af[ks], acc, 0, 0, 0);
        }

        // EPI: g[r] = -2*dot + cbn; codes crow(r,kh) of tile tgBase+t, row = cl
        float gv[16], m = 1e30f;
        #pragma unroll
        for (int r = 0; r < 16; ++r) {
            gv[r] = fmaf(-2.f, acc[r], cbnv[r]);
            m = fminf(m, gv[r]);
        }
        m = fminf(m, __shfl_xor(m, 32, 64));        // other code-half, same row
        rmin = fminf(rmin, m);                      // running min incl. this tile
        float thr = rmin + dlt;
        #pragma unroll
        for (int r = 0; r < 16; ++r) {
            if (gv[r] <= thr) {
                u32 code = (u32)((tgBase + t) * 32 + (r & 3) + 8 * (r >> 2) + 4 * kh);
                float mg = g0; int mi = 0;
                if (g1 > mg) { mg = g1; mi = 1; }
                if (g2 > mg) { mg = g2; mi = 2; }
                if (g3 > mg) { mg = g3; mi = 3; }
                if (g4 > mg) { mg = g4; mi = 4; }
                if (g5 > mg) { mg = g5; mi = 5; }
                if (mg > thr) {         // stale/empty: provably outside final window
                    if      (mi == 0) { g0 = gv[r]; s0 = code; }
                    else if (mi == 1) { g1 = gv[r]; s1 = code; }
                    else if (mi == 2) { g2 = gv[r]; s2 = code; }
                    else if (mi == 3) { g3 = gv[r]; s3 = code; }
                    else if (mi == 4) { g4 = gv[r]; s4 = code; }
                    else              { g5 = gv[r]; s5 = code; }
                } else {                // 7 fresh at once: ~never (bf16 window)
                    exact_rerank(X, CB, xx, cbn, myrow, (int)code, best);
                }
            }
        }
    }

    // post-loop: exact fp32 rerank of slots still within the FINAL window
    float thrF = rmin + dlt;
    if (g0 <= thrF) exact_rerank(X, CB, xx, cbn, myrow, (int)s0, best);
    if (g1 <= thrF) exact_rerank(X, CB, xx, cbn, myrow, (int)s1, best);
    if (g2 <= thrF) exact_rerank(X, CB, xx, cbn, myrow, (int)s2, best);
    if (g3 <= thrF) exact_rerank(X, CB, xx, cbn, myrow, (int)s3, best);
    if (g4 <= thrF) exact_rerank(X, CB, xx, cbn, myrow, (int)s4, best);
    if (g5 <= thrF) exact_rerank(X, CB, xx, cbn, myrow, (int)s5, best);
#undef STAGE
}

// ---------- kernel 3: gather e, Householder STE ----------
__global__ __launch_bounds__(256) void k_epilogue(const float* __restrict__ X,
                                                  const float* __restrict__ CB,
                                                  const u64* __restrict__ best,
                                                  float* __restrict__ Eout,
                                                  float* __restrict__ Sout) {
    int r    = blockIdx.x * 4 + (threadIdx.x >> 6);
    int lane = threadIdx.x & 63;
    int idx  = (int)(best[r] & 0xffffffffull);

    float4 xv = *reinterpret_cast<const float4*>(X  + (size_t)r   * COLS + lane * 4);
    float4 ev = *reinterpret_cast<const float4*>(CB + (size_t)idx * COLS + lane * 4);

    float xn2 = wave_sum(dot4(xv, xv));
    float en2 = wave_sum(dot4(ev, ev));
    float xn = sqrtf(xn2), en = sqrtf(en2);
    float invx = 1.f / fmaxf(xn, EPSF);
    float inve = 1.f / fmaxf(en, EPSF);

    float4 xd, ed, sd0;
    xd.x = xv.x*invx; xd.y = xv.y*invx; xd.z = xv.z*invx; xd.w = xv.w*invx;
    ed.x = ev.x*inve; ed.y = ev.y*inve; ed.z = ev.z*inve; ed.w = ev.w*inve;
    sd0.x = xd.x+ed.x; sd0.y = xd.y+ed.y; sd0.z = xd.z+ed.z; sd0.w = xd.w+ed.w;

    float sdn2 = wave_sum(dot4(sd0, sd0));
    float p1   = wave_sum(dot4(sd0, xv));
    float p2   = wave_sum(dot4(xd,  xv));
    float invs = 1.f / fmaxf(sqrtf(sdn2), EPSF);

    float csd = -2.f * invs * invs * p1;
    float ced =  2.f * p2;
    float4 rr;
    rr.x = fmaf(csd, sd0.x, fmaf(ced, ed.x, xv.x));
    rr.y = fmaf(csd, sd0.y, fmaf(ced, ed.y, xv.y));
    rr.z = fmaf(csd, sd0.z, fmaf(ced, ed.z, xv.z));
    rr.w = fmaf(csd, sd0.w, fmaf(ced, ed.w, xv.w));
    float sc = en * invx;
    float4 sv; sv.x = rr.x*sc; sv.y = rr.y*sc; sv.z = rr.z*sc; sv.w = rr.w*sc;

    *reinterpret_cast<float4*>(Eout + (size_t)r * COLS + lane * 4) = ev;
    *reinterpret_cast<float4*>(Sout + (size_t)r * COLS + lane * 4) = sv;
}

// ---------- launcher ----------
extern "C" void kernel_launch(void* const* d_in, const int* in_sizes, int n_in,
                              void* d_out, int out_size, void* d_ws, size_t ws_size,
                              hipStream_t stream) {
    const float* x  = (const float*)d_in[0];
    const float* fc = (const float*)d_in[1];
    const float* Wi = (const float*)d_in[2];
    const float* Wo = (const float*)d_in[3];

    // ws layout (~5 MB)
    char* ws = (char*)d_ws;
    u64*   best    = (u64*)ws;                            ws += (size_t)ROWS * 8;
    float* CBws    = (float*)ws;                          ws += (size_t)Nn * COLS * 4;
    float* cbn     = (float*)ws;                          ws += (size_t)Nn * 4;
    float* cbn_f   = (float*)ws;                          ws += (size_t)Nn * 4;
    float* xx      = (float*)ws;                          ws += (size_t)ROWS * 4;
    u32*   cbn_max = (u32*)ws;

    // bf16 copies live in d_out (128 MiB), only overwritten by k_epilogue at
    // the very end: Xh = 32 MiB at offset 0, CBf = 2 MiB at offset 64 MiB.
    short* Xh  = (short*)d_out;
    short* CBf = (short*)((char*)d_out + (64u << 20));

    float* Eout = (float*)d_out;
    float* Sout = Eout + (size_t)ROWS * COLS;

    k_prep<<<ROWS / 4, 256, 0, stream>>>(x, Xh, xx, best);
    k_codebook<<<Nn, 256, 0, stream>>>(fc, Wi, Wo, CBws, CBf, cbn, cbn_f);
    k_reduce_cbn<<<1, 256, 0, stream>>>(cbn, cbn_max);
    k_screen_fused<<<(ROWS / 128) * 2, 256, 0, stream>>>(Xh, CBf, x, CBws, cbn,
                                                         cbn_f, xx, best, cbn_max);
    k_epilogue<<<ROWS / 4, 256, 0, stream>>>(x, CBws, best, Eout, Sout);
}